// Round 1
// baseline (2478.778 us; speedup 1.0000x reference)
//
#include <hip/hip_runtime.h>
#include <hip/hip_bf16.h>
#include <math.h>

#define B_   2
#define S_   2048
#define D_   2048
#define H_   16
#define KVH_ 4
#define HD_  128
#define M_   (B_*S_)      // 4096
#define SCALE 0.08838834764831845f

// ---------------------------------------------------------------------------
// GEMM 1: QKV projection.  C = hidden @ W^T with W in {q_w,k_w,v_w} by n-range.
// Tile 128x128, K-chunk 16, 256 threads, 8x8 microtile.
// Epilogue scatters Q -> [B][H][S][HD], K/V -> [B][KVH][S][HD].
// ---------------------------------------------------------------------------
__global__ __launch_bounds__(256) void gemm_qkv(
    const float* __restrict__ A,    // [4096][2048]
    const float* __restrict__ qw,   // [2048][2048]
    const float* __restrict__ kw,   // [512][2048]
    const float* __restrict__ vw,   // [512][2048]
    float* __restrict__ Qo, float* __restrict__ Ko, float* __restrict__ Vo)
{
    __shared__ float As[16][136];   // k-major (transposed on load)
    __shared__ float Bs[16][136];

    const int n0 = blockIdx.x * 128;
    const int m0 = blockIdx.y * 128;
    const float* W; int nb; int which;
    if (n0 < 2048)      { W = qw; nb = n0;        which = 0; }
    else if (n0 < 2560) { W = kw; nb = n0 - 2048; which = 1; }
    else                { W = vw; nb = n0 - 2560; which = 2; }

    const int t  = threadIdx.x;
    const int tx = t & 15, ty = t >> 4;
    const int r0 = ty * 8;          // microtile rows (m)
    const int c0 = tx * 8;          // microtile cols (n)

    float acc[8][8];
    #pragma unroll
    for (int i = 0; i < 8; ++i)
        #pragma unroll
        for (int j = 0; j < 8; ++j) acc[i][j] = 0.f;

    for (int k0 = 0; k0 < 2048; k0 += 16) {
        #pragma unroll
        for (int u = 0; u < 2; ++u) {
            int f = t + u * 256;           // 0..511 float4 slots
            int row = f >> 2;              // 0..127
            int k4  = (f & 3) * 4;         // 0,4,8,12
            float4 a = *(const float4*)&A[(size_t)(m0 + row) * 2048 + k0 + k4];
            As[k4+0][row] = a.x; As[k4+1][row] = a.y;
            As[k4+2][row] = a.z; As[k4+3][row] = a.w;
            float4 b = *(const float4*)&W[(size_t)(nb + row) * 2048 + k0 + k4];
            Bs[k4+0][row] = b.x; Bs[k4+1][row] = b.y;
            Bs[k4+2][row] = b.z; Bs[k4+3][row] = b.w;
        }
        __syncthreads();
        #pragma unroll
        for (int kk = 0; kk < 16; ++kk) {
            float4 a0 = *(const float4*)&As[kk][r0];
            float4 a1 = *(const float4*)&As[kk][r0 + 4];
            float4 b0 = *(const float4*)&Bs[kk][c0];
            float4 b1 = *(const float4*)&Bs[kk][c0 + 4];
            float av[8] = {a0.x,a0.y,a0.z,a0.w,a1.x,a1.y,a1.z,a1.w};
            float bv[8] = {b0.x,b0.y,b0.z,b0.w,b1.x,b1.y,b1.z,b1.w};
            #pragma unroll
            for (int i = 0; i < 8; ++i)
                #pragma unroll
                for (int j = 0; j < 8; ++j)
                    acc[i][j] += av[i] * bv[j];
        }
        __syncthreads();
    }

    // epilogue: scatter into head-major layouts
    const int nloc = nb + c0;
    const int hh = nloc >> 7;       // head index within its matrix
    const int d  = nloc & 127;      // c0 is 8-aligned, 8 cols stay in one head
    float* dst = (which == 0) ? Qo : (which == 1 ? Ko : Vo);
    const int nheads_stride = (which == 0) ? H_ : KVH_;
    #pragma unroll
    for (int i = 0; i < 8; ++i) {
        int m = m0 + r0 + i;
        int bb = m >> 11;           // / 2048
        int s  = m & 2047;
        size_t off = ((size_t)(bb * nheads_stride + hh) * S_ + s) * HD_ + d;
        float4 v0 = make_float4(acc[i][0], acc[i][1], acc[i][2], acc[i][3]);
        float4 v1 = make_float4(acc[i][4], acc[i][5], acc[i][6], acc[i][7]);
        *(float4*)&dst[off]     = v0;
        *(float4*)&dst[off + 4] = v1;
    }
}

// ---------------------------------------------------------------------------
// RMSNorm + RoPE in place on Q' and K'.  One wave (64 lanes) per 128-elem row.
// Lane handles d = lane and d = lane+64 (the rotate_half pair).
// ---------------------------------------------------------------------------
__global__ __launch_bounds__(256) void norm_rope(
    float* __restrict__ Qb, float* __restrict__ Kb,
    const float* __restrict__ cosb, const float* __restrict__ sinb,
    const float* __restrict__ qnw, const float* __restrict__ knw)
{
    const int rid  = blockIdx.x * 4 + (threadIdx.x >> 6);
    const int lane = threadIdx.x & 63;
    float* row; const float* w; int s;
    if (rid < B_ * H_ * S_) {                       // 65536 Q rows
        row = Qb + (size_t)rid * HD_;
        w = qnw; s = rid & (S_ - 1);
    } else {
        int r2 = rid - B_ * H_ * S_;                // 16384 K rows
        row = Kb + (size_t)r2 * HD_;
        w = knw; s = r2 & (S_ - 1);
    }
    float x0 = row[lane], x1 = row[lane + 64];
    float ss = x0 * x0 + x1 * x1;
    #pragma unroll
    for (int off = 1; off < 64; off <<= 1) ss += __shfl_xor(ss, off);
    float r = rsqrtf(ss * (1.f / 128.f) + 1e-6f);
    float n0 = x0 * r * w[lane];
    float n1 = x1 * r * w[lane + 64];
    float c0 = cosb[s * HD_ + lane], c1 = cosb[s * HD_ + lane + 64];
    float s0 = sinb[s * HD_ + lane], s1 = sinb[s * HD_ + lane + 64];
    row[lane]      = n0 * c0 - n1 * s0;   // d<64:  x*c - x[d+64]*s
    row[lane + 64] = n1 * c1 + n0 * s1;   // d>=64: x*c + x[d-64]*s
}

// ---------------------------------------------------------------------------
// Flash attention, fp32.  Block = (b, h, 64 q-rows).  K-tiles of 64.
// LDS tiles 64x128 with float4 XOR swizzle (kills stride-128 bank conflicts).
// ---------------------------------------------------------------------------
__device__ __forceinline__ int swz(int r, int c) {
    return r * 128 + ((((c >> 2) ^ ((r >> 2) & 7)) << 2) | (c & 3));
}

__global__ __launch_bounds__(256) void attn_kernel(
    const float* __restrict__ Q,    // [B][H][S][128]
    const float* __restrict__ K,    // [B][KVH][S][128]
    const float* __restrict__ V,
    float* __restrict__ AO)         // [B][S][2048]
{
    __shared__ float Qs[64 * 128];
    __shared__ float Ks[64 * 128];
    __shared__ float Vs[64 * 128];
    __shared__ float Ss[64 * 65];
    __shared__ float m_sm[64], l_sm[64], al_sm[64];

    const int bh  = blockIdx.y;                 // 0..31
    const int bb  = bh >> 4, h = bh & 15;
    const int kvh = h >> 2;                     // groups = 4
    const int q0  = blockIdx.x * 64;
    const float* Qp = Q + ((size_t)(bb * H_ + h) * S_ + q0) * HD_;
    const float* Kp = K + ((size_t)(bb * KVH_ + kvh) * S_) * HD_;
    const float* Vp = V + ((size_t)(bb * KVH_ + kvh) * S_) * HD_;

    const int t = threadIdx.x;
    // load Q tile (64x128)
    #pragma unroll
    for (int u = 0; u < 8; ++u) {
        int f = t + u * 256; int row = f >> 5; int c = (f & 31) * 4;
        *(float4*)&Qs[swz(row, c)] = *(const float4*)&Qp[(size_t)row * 128 + c];
    }
    if (t < 64) { m_sm[t] = -1e30f; l_sm[t] = 0.f; }

    float acc[4][8];
    #pragma unroll
    for (int i = 0; i < 4; ++i)
        #pragma unroll
        for (int j = 0; j < 8; ++j) acc[i][j] = 0.f;

    const int qr = (t >> 4) * 4;   // QK: q-row group
    const int kc = (t & 15) * 4;   // QK: k-col group
    const int sr = t >> 2, sq = t & 3;   // softmax mapping
    const int py = t & 15, px = t >> 4;  // PV mapping
    __syncthreads();

    for (int kt = 0; kt < 32; ++kt) {
        const float* Kt = Kp + (size_t)kt * 64 * 128;
        const float* Vt = Vp + (size_t)kt * 64 * 128;
        #pragma unroll
        for (int u = 0; u < 8; ++u) {
            int f = t + u * 256; int row = f >> 5; int c = (f & 31) * 4;
            *(float4*)&Ks[swz(row, c)] = *(const float4*)&Kt[(size_t)row * 128 + c];
            *(float4*)&Vs[swz(row, c)] = *(const float4*)&Vt[(size_t)row * 128 + c];
        }
        __syncthreads();

        // --- QK^T: 4x4 scores per thread ---
        float sc[4][4];
        #pragma unroll
        for (int i = 0; i < 4; ++i)
            #pragma unroll
            for (int j = 0; j < 4; ++j) sc[i][j] = 0.f;
        for (int d = 0; d < 128; d += 4) {
            float4 qa[4], kb[4];
            #pragma unroll
            for (int i = 0; i < 4; ++i) qa[i] = *(const float4*)&Qs[swz(qr + i, d)];
            #pragma unroll
            for (int j = 0; j < 4; ++j) kb[j] = *(const float4*)&Ks[swz(kc + j, d)];
            #pragma unroll
            for (int i = 0; i < 4; ++i)
                #pragma unroll
                for (int j = 0; j < 4; ++j)
                    sc[i][j] += qa[i].x*kb[j].x + qa[i].y*kb[j].y
                              + qa[i].z*kb[j].z + qa[i].w*kb[j].w;
        }
        #pragma unroll
        for (int i = 0; i < 4; ++i)
            #pragma unroll
            for (int j = 0; j < 4; ++j)
                Ss[(qr + i) * 65 + kc + j] = sc[i][j] * SCALE;
        __syncthreads();

        // --- online softmax: 4 lanes per row ---
        float mx = -1e30f;
        #pragma unroll
        for (int c2 = 0; c2 < 16; ++c2)
            mx = fmaxf(mx, Ss[sr * 65 + sq * 16 + c2]);
        mx = fmaxf(mx, __shfl_xor(mx, 1));
        mx = fmaxf(mx, __shfl_xor(mx, 2));
        float mo = m_sm[sr];
        float mn = fmaxf(mo, mx);
        float psum = 0.f;
        #pragma unroll
        for (int c2 = 0; c2 < 16; ++c2) {
            float p = __expf(Ss[sr * 65 + sq * 16 + c2] - mn);
            Ss[sr * 65 + sq * 16 + c2] = p;
            psum += p;
        }
        psum += __shfl_xor(psum, 1);
        psum += __shfl_xor(psum, 2);
        if (sq == 0) {
            float al = __expf(mo - mn);
            m_sm[sr]  = mn;
            l_sm[sr]  = l_sm[sr] * al + psum;
            al_sm[sr] = al;
        }
        __syncthreads();

        // --- PV accumulate: 4 rows x 8 cols per thread ---
        float al4[4];
        #pragma unroll
        for (int i = 0; i < 4; ++i) al4[i] = al_sm[py * 4 + i];
        #pragma unroll
        for (int i = 0; i < 4; ++i)
            #pragma unroll
            for (int j = 0; j < 8; ++j) acc[i][j] *= al4[i];
        for (int kk = 0; kk < 64; ++kk) {
            float4 va = *(const float4*)&Vs[swz(kk, px * 8)];
            float4 vb = *(const float4*)&Vs[swz(kk, px * 8 + 4)];
            float pr[4];
            #pragma unroll
            for (int i = 0; i < 4; ++i) pr[i] = Ss[(py * 4 + i) * 65 + kk];
            #pragma unroll
            for (int i = 0; i < 4; ++i) {
                acc[i][0] += pr[i] * va.x; acc[i][1] += pr[i] * va.y;
                acc[i][2] += pr[i] * va.z; acc[i][3] += pr[i] * va.w;
                acc[i][4] += pr[i] * vb.x; acc[i][5] += pr[i] * vb.y;
                acc[i][6] += pr[i] * vb.z; acc[i][7] += pr[i] * vb.w;
            }
        }
        __syncthreads();
    }

    // epilogue: AO[b][s][h*128 + d]
    #pragma unroll
    for (int i = 0; i < 4; ++i) {
        int r = py * 4 + i;
        int s = q0 + r;
        float inv = 1.f / l_sm[r];
        size_t off = ((size_t)bb * S_ + s) * 2048 + h * 128 + px * 8;
        float4 o0 = make_float4(acc[i][0]*inv, acc[i][1]*inv, acc[i][2]*inv, acc[i][3]*inv);
        float4 o1 = make_float4(acc[i][4]*inv, acc[i][5]*inv, acc[i][6]*inv, acc[i][7]*inv);
        *(float4*)&AO[off]     = o0;
        *(float4*)&AO[off + 4] = o1;
    }
}

// ---------------------------------------------------------------------------
// GEMM 2: output projection.  out = AO @ o_w^T.
// ---------------------------------------------------------------------------
__global__ __launch_bounds__(256) void gemm_o(
    const float* __restrict__ A,    // [4096][2048]
    const float* __restrict__ W,    // [2048][2048]
    float* __restrict__ C)          // [4096][2048]
{
    __shared__ float As[16][136];
    __shared__ float Bs[16][136];

    const int n0 = blockIdx.x * 128;
    const int m0 = blockIdx.y * 128;
    const int t  = threadIdx.x;
    const int tx = t & 15, ty = t >> 4;
    const int r0 = ty * 8;
    const int c0 = tx * 8;

    float acc[8][8];
    #pragma unroll
    for (int i = 0; i < 8; ++i)
        #pragma unroll
        for (int j = 0; j < 8; ++j) acc[i][j] = 0.f;

    for (int k0 = 0; k0 < 2048; k0 += 16) {
        #pragma unroll
        for (int u = 0; u < 2; ++u) {
            int f = t + u * 256;
            int row = f >> 2;
            int k4  = (f & 3) * 4;
            float4 a = *(const float4*)&A[(size_t)(m0 + row) * 2048 + k0 + k4];
            As[k4+0][row] = a.x; As[k4+1][row] = a.y;
            As[k4+2][row] = a.z; As[k4+3][row] = a.w;
            float4 b = *(const float4*)&W[(size_t)(n0 + row) * 2048 + k0 + k4];
            Bs[k4+0][row] = b.x; Bs[k4+1][row] = b.y;
            Bs[k4+2][row] = b.z; Bs[k4+3][row] = b.w;
        }
        __syncthreads();
        #pragma unroll
        for (int kk = 0; kk < 16; ++kk) {
            float4 a0 = *(const float4*)&As[kk][r0];
            float4 a1 = *(const float4*)&As[kk][r0 + 4];
            float4 b0 = *(const float4*)&Bs[kk][c0];
            float4 b1 = *(const float4*)&Bs[kk][c0 + 4];
            float av[8] = {a0.x,a0.y,a0.z,a0.w,a1.x,a1.y,a1.z,a1.w};
            float bv[8] = {b0.x,b0.y,b0.z,b0.w,b1.x,b1.y,b1.z,b1.w};
            #pragma unroll
            for (int i = 0; i < 8; ++i)
                #pragma unroll
                for (int j = 0; j < 8; ++j)
                    acc[i][j] += av[i] * bv[j];
        }
        __syncthreads();
    }

    #pragma unroll
    for (int i = 0; i < 8; ++i) {
        int m = m0 + r0 + i;
        size_t off = (size_t)m * 2048 + n0 + c0;
        float4 v0 = make_float4(acc[i][0], acc[i][1], acc[i][2], acc[i][3]);
        float4 v1 = make_float4(acc[i][4], acc[i][5], acc[i][6], acc[i][7]);
        *(float4*)&C[off]     = v0;
        *(float4*)&C[off + 4] = v1;
    }
}

// ---------------------------------------------------------------------------
extern "C" void kernel_launch(void* const* d_in, const int* in_sizes, int n_in,
                              void* d_out, int out_size, void* d_ws, size_t ws_size,
                              hipStream_t stream) {
    (void)in_sizes; (void)n_in; (void)out_size; (void)ws_size;
    const float* hid = (const float*)d_in[0];
    const float* cosb = (const float*)d_in[1];
    const float* sinb = (const float*)d_in[2];
    const float* qw  = (const float*)d_in[3];
    const float* kw  = (const float*)d_in[4];
    const float* vw  = (const float*)d_in[5];
    const float* ow  = (const float*)d_in[6];
    const float* qnw = (const float*)d_in[7];
    const float* knw = (const float*)d_in[8];

    float* ws = (float*)d_ws;
    float* Qb = ws;                       // 8388608 floats  [B][H][S][HD]
    float* Kb = ws + 8388608;             // 2097152 floats  [B][KVH][S][HD]
    float* Vb = ws + 10485760;            // 2097152 floats
    float* AO = ws + 12582912;            // 8388608 floats  [B][S][2048]

    gemm_qkv<<<dim3(24, 32), 256, 0, stream>>>(hid, qw, kw, vw, Qb, Kb, Vb);
    norm_rope<<<20480, 256, 0, stream>>>(Qb, Kb, cosb, sinb, qnw, knw);
    attn_kernel<<<dim3(32, 32), 256, 0, stream>>>(Qb, Kb, Vb, AO);
    gemm_o<<<dim3(16, 32), 256, 0, stream>>>(AO, ow, (float*)d_out);
}

// Round 2
// 277.950 us; speedup vs baseline: 8.9181x; 8.9181x over previous
//
#include <hip/hip_runtime.h>
#include <hip/hip_bf16.h>
#include <math.h>

#define B_   2
#define S_   2048
#define D_   2048
#define H_   16
#define KVH_ 4
#define HD_  128
#define SCALE 0.08838834764831845f

typedef unsigned short u16;
typedef __attribute__((ext_vector_type(8))) short bf16x8;   // 8 bf16 (4 VGPRs)
typedef __attribute__((ext_vector_type(4))) float f32x4;

__device__ __forceinline__ u16 f2bf(float x) {
    union { float f; unsigned int u; } v; v.f = x;
    unsigned int r = v.u + 0x7fffu + ((v.u >> 16) & 1u);
    return (u16)(r >> 16);
}
__device__ __forceinline__ float bf2f(u16 b) {
    union { float f; unsigned int u; } v; v.u = ((unsigned int)b) << 16;
    return v.f;
}
// async global->LDS, 16B per lane. LDS dest = uniform base + lane*16 (linear);
// swizzle must be applied on the per-lane GLOBAL source address (rule 21).
__device__ __forceinline__ void gload16(const void* g, void* lds) {
    __builtin_amdgcn_global_load_lds(
        (const __attribute__((address_space(1))) unsigned int*)g,
        (__attribute__((address_space(3))) unsigned int*)lds, 16, 0, 0);
}

// ---------------------------------------------------------------------------
// fp32 -> bf16 convert (vectorized)
// ---------------------------------------------------------------------------
__global__ __launch_bounds__(256) void f2b_kernel(
    const float* __restrict__ s, u16* __restrict__ d, int n4)
{
    int i = blockIdx.x * 256 + threadIdx.x;
    if (i >= n4) return;
    float4 v = ((const float4*)s)[i];
    ushort4 o = make_ushort4(f2bf(v.x), f2bf(v.y), f2bf(v.z), f2bf(v.w));
    ((ushort4*)d)[i] = o;
}

// ---------------------------------------------------------------------------
// bf16 MFMA GEMM, m97 structure: 128x128 tile, BK=64, 4 waves (2x2 of 64x64),
// global_load_lds w=16 with pre-swizzled source; XOR-swizzled ds_read_b128.
// MODE 0: QKV projection with head-major scatter epilogue (V transposed).
// MODE 1: O projection, fp32 output.
// ---------------------------------------------------------------------------
template<int MODE>
__global__ __launch_bounds__(256) void gemm_bf16(
    const u16* __restrict__ A,    // [4096][2048] bf16
    const u16* __restrict__ Bw,   // [N][2048] bf16 (rows = output cols)
    u16* __restrict__ Qo, u16* __restrict__ Ko, u16* __restrict__ Vt,
    float* __restrict__ Co)
{
    __shared__ u16 As[128 * 64];
    __shared__ u16 Bs[128 * 64];

    const int t  = threadIdx.x;
    const int w  = t >> 6, l = t & 63;
    const int wm = w >> 1, wn = w & 1;
    const int lr = l & 15, lh = l >> 4;
    const int n0 = blockIdx.x * 128;
    const int m0 = blockIdx.y * 128;

    f32x4 acc[4][4];
    #pragma unroll
    for (int i = 0; i < 4; ++i)
        #pragma unroll
        for (int j = 0; j < 4; ++j)
            acc[i][j] = (f32x4)0.f;

    // staging geometry (per wave: 4 x 1KB issues per tile per matrix)
    const int x  = (w * 4) * 1024 + l * 16;   // base chunk byte for u=0
    for (int k0 = 0; k0 < 2048; k0 += 64) {
        #pragma unroll
        for (int u = 0; u < 4; ++u) {
            int xb = x + u * 1024;
            int r  = xb >> 7;                 // LDS row (128B rows)
            int c  = xb & 127;
            int cs = c ^ ((r & 7) << 4);      // inverse swizzle on source
            gload16(&A[(size_t)(m0 + r) * 2048 + k0 + (cs >> 1)], &As[(w * 4 + u) * 512]);
            gload16(&Bw[(size_t)(n0 + r) * 2048 + k0 + (cs >> 1)], &Bs[(w * 4 + u) * 512]);
        }
        __syncthreads();
        #pragma unroll
        for (int kc = 0; kc < 2; ++kc) {
            bf16x8 af[4], bfr[4];
            #pragma unroll
            for (int i = 0; i < 4; ++i) {
                int row = wm * 64 + i * 16 + lr;
                int byt = row * 128 + ((kc * 64 + lh * 16) ^ ((row & 7) << 4));
                af[i] = *(const bf16x8*)&As[byt >> 1];
                int rob = wn * 64 + i * 16 + lr;
                int byb = rob * 128 + ((kc * 64 + lh * 16) ^ ((rob & 7) << 4));
                bfr[i] = *(const bf16x8*)&Bs[byb >> 1];
            }
            #pragma unroll
            for (int i = 0; i < 4; ++i)
                #pragma unroll
                for (int j = 0; j < 4; ++j)
                    acc[i][j] = __builtin_amdgcn_mfma_f32_16x16x32_bf16(
                        af[i], bfr[j], acc[i][j], 0, 0, 0);
        }
        __syncthreads();
    }

    // epilogue.  C/D layout: row = (l>>4)*4 + reg, col = l&15  [m89-verified]
    #pragma unroll
    for (int i = 0; i < 4; ++i) {
        #pragma unroll
        for (int j = 0; j < 4; ++j) {
            int col = n0 + wn * 64 + j * 16 + lr;
            #pragma unroll
            for (int r = 0; r < 4; ++r) {
                int m = m0 + wm * 64 + i * 16 + lh * 4 + r;
                float v = acc[i][j][r];
                if (MODE == 0) {
                    int bb = m >> 11, s = m & 2047;
                    if (col < 2048) {
                        int hh = col >> 7, d = col & 127;
                        Qo[((size_t)(bb * H_ + hh) * S_ + s) * HD_ + d] = f2bf(v);
                    } else if (col < 2560) {
                        int c2 = col - 2048; int hh = c2 >> 7, d = c2 & 127;
                        Ko[((size_t)(bb * KVH_ + hh) * S_ + s) * HD_ + d] = f2bf(v);
                    } else {
                        int c2 = col - 2560; int hh = c2 >> 7, d = c2 & 127;
                        Vt[((size_t)(bb * KVH_ + hh) * HD_ + d) * S_ + s] = f2bf(v);
                    }
                } else {
                    Co[(size_t)m * 2048 + col] = v;
                }
            }
        }
    }
}

// ---------------------------------------------------------------------------
// RMSNorm + RoPE in place (bf16).  One wave per 128-elem row; lane owns
// elems {2l, 2l+1}; rotate-half partner d+-64 fetched via __shfl_xor(.,32).
// Softmax scale folded into Q here.
// ---------------------------------------------------------------------------
__global__ __launch_bounds__(256) void norm_rope(
    u16* __restrict__ Qb, u16* __restrict__ Kb,
    const float* __restrict__ cosb, const float* __restrict__ sinb,
    const float* __restrict__ qnw, const float* __restrict__ knw)
{
    const int rid = blockIdx.x * 4 + (threadIdx.x >> 6);
    const int l   = threadIdx.x & 63;
    u16* row; const float* wn; int s; float sc;
    if (rid < B_ * H_ * S_) {
        row = Qb + (size_t)rid * HD_; wn = qnw; s = rid & (S_ - 1); sc = SCALE;
    } else {
        int r2 = rid - B_ * H_ * S_;
        row = Kb + (size_t)r2 * HD_; wn = knw; s = r2 & (S_ - 1); sc = 1.f;
    }
    unsigned int u = *(const unsigned int*)&row[2 * l];
    float x0 = bf2f((u16)(u & 0xffff)), x1 = bf2f((u16)(u >> 16));
    float ss = x0 * x0 + x1 * x1;
    #pragma unroll
    for (int off = 1; off < 64; off <<= 1) ss += __shfl_xor(ss, off);
    float rr = rsqrtf(ss * (1.f / 128.f) + 1e-6f);
    float n0 = x0 * rr * wn[2 * l];
    float n1 = x1 * rr * wn[2 * l + 1];
    float p0 = __shfl_xor(n0, 32);
    float p1 = __shfl_xor(n1, 32);
    float sg = (l < 32) ? -1.f : 1.f;
    const float* cp = cosb + s * HD_;
    const float* sp = sinb + s * HD_;
    float o0 = (n0 * cp[2 * l]     + sg * p0 * sp[2 * l])     * sc;
    float o1 = (n1 * cp[2 * l + 1] + sg * p1 * sp[2 * l + 1]) * sc;
    unsigned int o = (unsigned int)f2bf(o0) | ((unsigned int)f2bf(o1) << 16);
    *(unsigned int*)&row[2 * l] = o;
}

// ---------------------------------------------------------------------------
// Flash attention, bf16 MFMA.  Block = 4 waves x 32 q-rows = 128 q-rows per
// (b,h).  KV tiles of 64 staged via swizzled global_load_lds.  Online softmax
// in registers (16-lane shfl groups).  P goes through per-wave padded LDS.
// ---------------------------------------------------------------------------
__global__ __launch_bounds__(256, 2) void attn_mfma(
    const u16* __restrict__ Q,    // [B*H][S][128], scale pre-folded
    const u16* __restrict__ K,    // [B*KVH][S][128]
    const u16* __restrict__ Vt,   // [B*KVH][128][S]
    u16* __restrict__ AO)         // [B][S][2048]
{
    __shared__ u16 Ks[64 * 128];        // rows 256B, XOR-swizzled
    __shared__ u16 Vs[128 * 64];        // rows 128B, XOR-swizzled
    __shared__ u16 Ps[4][32 * 72];      // per-wave P, stride 72 (144B, 16B-aligned)

    const int t = threadIdx.x, w = t >> 6, l = t & 63;
    const int lr = l & 15, lh = l >> 4;
    const int bh = blockIdx.y;
    const int bb = bh >> 4, h = bh & 15;
    const int kv = bb * KVH_ + (h >> 2);
    const int q0 = blockIdx.x * 128 + w * 32;

    const u16* Qp = Q + ((size_t)bh * S_ + q0) * HD_;
    const u16* Kp = K + (size_t)kv * S_ * HD_;
    const u16* Vp = Vt + (size_t)kv * HD_ * S_;

    // Q fragments in registers for the whole kernel (A-frag: row=l&15, k=(l>>4)*8+j)
    bf16x8 aq[2][4];
    #pragma unroll
    for (int rb = 0; rb < 2; ++rb)
        #pragma unroll
        for (int dc = 0; dc < 4; ++dc)
            aq[rb][dc] = *(const bf16x8*)&Qp[(size_t)(rb * 16 + lr) * 128 + dc * 32 + lh * 8];

    f32x4 oacc[2][8];
    #pragma unroll
    for (int rb = 0; rb < 2; ++rb)
        #pragma unroll
        for (int db = 0; db < 8; ++db)
            oacc[rb][db] = (f32x4)0.f;
    float mrun[2][4], lrun[2][4];
    #pragma unroll
    for (int rb = 0; rb < 2; ++rb)
        #pragma unroll
        for (int r = 0; r < 4; ++r) { mrun[rb][r] = -1e30f; lrun[rb][r] = 0.f; }

    for (int kt = 0; kt < S_ / 64; ++kt) {
        const int k0 = kt * 64;
        #pragma unroll
        for (int u = 0; u < 4; ++u) {
            int xb = (w * 4 + u) * 1024 + l * 16;
            int rk = xb >> 8, ck = xb & 255;          // K tile: 64 rows x 256B
            gload16(&Kp[(size_t)(k0 + rk) * 128 + ((ck ^ ((rk & 7) << 4)) >> 1)],
                    &Ks[(w * 4 + u) * 512]);
            int rv = xb >> 7, cv = xb & 127;          // V tile: 128 rows x 128B
            gload16(&Vp[(size_t)rv * S_ + k0 + ((cv ^ ((rv & 7) << 4)) >> 1)],
                    &Vs[(w * 4 + u) * 512]);
        }
        __syncthreads();

        // --- QK^T (scores include scale via folded Q) ---
        f32x4 sacc[2][4];
        #pragma unroll
        for (int rb = 0; rb < 2; ++rb)
            #pragma unroll
            for (int kb = 0; kb < 4; ++kb) sacc[rb][kb] = (f32x4)0.f;
        #pragma unroll
        for (int kb = 0; kb < 4; ++kb) {
            bf16x8 kf[4];
            #pragma unroll
            for (int dc = 0; dc < 4; ++dc) {
                int row = kb * 16 + lr;
                int byt = row * 256 + ((dc * 64 + lh * 16) ^ ((row & 7) << 4));
                kf[dc] = *(const bf16x8*)&Ks[byt >> 1];
            }
            #pragma unroll
            for (int rb = 0; rb < 2; ++rb)
                #pragma unroll
                for (int dc = 0; dc < 4; ++dc)
                    sacc[rb][kb] = __builtin_amdgcn_mfma_f32_16x16x32_bf16(
                        aq[rb][dc], kf[dc], sacc[rb][kb], 0, 0, 0);
        }

        // --- online softmax (rows: rb*16 + lh*4 + r, reduce across 16-lane group) ---
        #pragma unroll
        for (int rb = 0; rb < 2; ++rb) {
            #pragma unroll
            for (int r = 0; r < 4; ++r) {
                float mx = fmaxf(fmaxf(sacc[rb][0][r], sacc[rb][1][r]),
                                 fmaxf(sacc[rb][2][r], sacc[rb][3][r]));
                mx = fmaxf(mx, __shfl_xor(mx, 1));
                mx = fmaxf(mx, __shfl_xor(mx, 2));
                mx = fmaxf(mx, __shfl_xor(mx, 4));
                mx = fmaxf(mx, __shfl_xor(mx, 8));
                float mo = mrun[rb][r];
                float mn = fmaxf(mo, mx);
                float al = __expf(mo - mn);
                mrun[rb][r] = mn;
                float ps = 0.f;
                #pragma unroll
                for (int kb = 0; kb < 4; ++kb) {
                    float p = __expf(sacc[rb][kb][r] - mn);
                    sacc[rb][kb][r] = p;
                    ps += p;
                }
                ps += __shfl_xor(ps, 1);
                ps += __shfl_xor(ps, 2);
                ps += __shfl_xor(ps, 4);
                ps += __shfl_xor(ps, 8);
                lrun[rb][r] = lrun[rb][r] * al + ps;
                #pragma unroll
                for (int db = 0; db < 8; ++db)
                    oacc[rb][db][r] *= al;
                int prow = rb * 16 + lh * 4 + r;
                #pragma unroll
                for (int kb = 0; kb < 4; ++kb)
                    Ps[w][prow * 72 + kb * 16 + lr] = f2bf(sacc[rb][kb][r]);
            }
        }
        asm volatile("s_waitcnt lgkmcnt(0)" ::: "memory");  // P writes visible to own wave

        // --- PV: O += P @ V  (B-frag from transposed V tile) ---
        #pragma unroll
        for (int kc = 0; kc < 2; ++kc) {
            bf16x8 pf[2];
            #pragma unroll
            for (int rb = 0; rb < 2; ++rb)
                pf[rb] = *(const bf16x8*)&Ps[w][(rb * 16 + lr) * 72 + kc * 32 + lh * 8];
            #pragma unroll
            for (int db = 0; db < 8; ++db) {
                int row = db * 16 + lr;
                int byt = row * 128 + ((kc * 64 + lh * 16) ^ ((row & 7) << 4));
                bf16x8 vf = *(const bf16x8*)&Vs[byt >> 1];
                #pragma unroll
                for (int rb = 0; rb < 2; ++rb)
                    oacc[rb][db] = __builtin_amdgcn_mfma_f32_16x16x32_bf16(
                        pf[rb], vf, oacc[rb][db], 0, 0, 0);
            }
        }
        __syncthreads();
    }

    // epilogue: AO[b][s][h*128 + d]
    #pragma unroll
    for (int rb = 0; rb < 2; ++rb) {
        #pragma unroll
        for (int r = 0; r < 4; ++r) {
            float inv = 1.f / lrun[rb][r];
            int s = q0 + rb * 16 + lh * 4 + r;
            size_t base = ((size_t)bb * S_ + s) * 2048 + h * 128;
            #pragma unroll
            for (int db = 0; db < 8; ++db)
                AO[base + db * 16 + lr] = f2bf(oacc[rb][db][r] * inv);
        }
    }
}

// ---------------------------------------------------------------------------
extern "C" void kernel_launch(void* const* d_in, const int* in_sizes, int n_in,
                              void* d_out, int out_size, void* d_ws, size_t ws_size,
                              hipStream_t stream) {
    (void)in_sizes; (void)n_in; (void)out_size; (void)ws_size;
    const float* hid  = (const float*)d_in[0];
    const float* cosb = (const float*)d_in[1];
    const float* sinb = (const float*)d_in[2];
    const float* qw   = (const float*)d_in[3];
    const float* kw   = (const float*)d_in[4];
    const float* vw   = (const float*)d_in[5];
    const float* ow   = (const float*)d_in[6];
    const float* qnw  = (const float*)d_in[7];
    const float* knw  = (const float*)d_in[8];

    u16* ws   = (u16*)d_ws;
    u16* hidB = ws;                         // 8,388,608
    u16* Wc   = ws + 8388608;               // 6,291,456  (qw|kw|vw rows)
    u16* owB  = ws + 14680064;              // 4,194,304
    u16* Qb   = ws + 18874368;              // 8,388,608  [B*H][S][128]
    u16* Kb   = ws + 27262976;              // 2,097,152  [B*KVH][S][128]
    u16* VtB  = ws + 29360128;              // 2,097,152  [B*KVH][128][S]
    u16* AO   = ws + 31457280;              // 8,388,608  [B][S][2048]

    f2b_kernel<<<8192, 256, 0, stream>>>(hid, hidB, 2097152);
    f2b_kernel<<<4096, 256, 0, stream>>>(qw, Wc, 1048576);
    f2b_kernel<<<1024, 256, 0, stream>>>(kw, Wc + 4194304, 262144);
    f2b_kernel<<<1024, 256, 0, stream>>>(vw, Wc + 5242880, 262144);
    f2b_kernel<<<4096, 256, 0, stream>>>(ow, owB, 1048576);

    gemm_bf16<0><<<dim3(24, 32), 256, 0, stream>>>(hidB, Wc, Qb, Kb, VtB, nullptr);
    norm_rope<<<20480, 256, 0, stream>>>(Qb, Kb, cosb, sinb, qnw, knw);
    attn_mfma<<<dim3(16, 32), 256, 0, stream>>>(Qb, Kb, VtB, AO);
    gemm_bf16<1><<<dim3(16, 32), 256, 0, stream>>>(AO, owB, nullptr, nullptr, nullptr,
                                                   (float*)d_out);
}

// Round 3
// 242.207 us; speedup vs baseline: 10.2341x; 1.1476x over previous
//
#include <hip/hip_runtime.h>
#include <hip/hip_bf16.h>
#include <math.h>

#define B_   2
#define S_   2048
#define D_   2048
#define H_   16
#define KVH_ 4
#define HD_  128
#define SCALE 0.08838834764831845f
#define LOG2E 1.44269504088896f

typedef unsigned short u16;
typedef unsigned int   u32;
typedef __attribute__((ext_vector_type(8)))  short bf16x8;   // 8 bf16 (4 VGPRs)
typedef __attribute__((ext_vector_type(4)))  float f32x4;
typedef __attribute__((ext_vector_type(16))) float f32x16;

__device__ __forceinline__ u16 f2bf(float x) {
    union { float f; unsigned int u; } v; v.f = x;
    unsigned int r = v.u + 0x7fffu + ((v.u >> 16) & 1u);
    return (u16)(r >> 16);
}
__device__ __forceinline__ float bf2f(u16 b) {
    union { float f; unsigned int u; } v; v.u = ((unsigned int)b) << 16;
    return v.f;
}
__device__ __forceinline__ u32 cvtpk(float lo, float hi) {
    u32 r;
    asm("v_cvt_pk_bf16_f32 %0, %1, %2" : "=v"(r) : "v"(lo), "v"(hi));
    return r;
}
// async global->LDS, 16B per lane. LDS dest = uniform base + lane*16 (linear);
// swizzle must be applied on the per-lane GLOBAL source address (rule 21).
__device__ __forceinline__ void gload16(const void* g, void* lds) {
    __builtin_amdgcn_global_load_lds(
        (const __attribute__((address_space(1))) unsigned int*)g,
        (__attribute__((address_space(3))) unsigned int*)lds, 16, 0, 0);
}

// ---------------------------------------------------------------------------
// fp32 -> bf16 convert (vectorized)
// ---------------------------------------------------------------------------
__global__ __launch_bounds__(256) void f2b_kernel(
    const float* __restrict__ s, u16* __restrict__ d, int n4)
{
    int i = blockIdx.x * 256 + threadIdx.x;
    if (i >= n4) return;
    float4 v = ((const float4*)s)[i];
    ushort4 o = make_ushort4(f2bf(v.x), f2bf(v.y), f2bf(v.z), f2bf(v.w));
    ((ushort4*)d)[i] = o;
}

// ---------------------------------------------------------------------------
// bf16 MFMA GEMM, m97 structure: 128x128 tile, BK=64, 4 waves (2x2 of 64x64),
// global_load_lds w=16 with pre-swizzled source; XOR-swizzled ds_read_b128.
// MODE 0: QKV projection with head-major scatter epilogue (V transposed).
// MODE 1: O projection, fp32 output.
// ---------------------------------------------------------------------------
template<int MODE>
__global__ __launch_bounds__(256) void gemm_bf16(
    const u16* __restrict__ A,    // [4096][2048] bf16
    const u16* __restrict__ Bw,   // [N][2048] bf16 (rows = output cols)
    u16* __restrict__ Qo, u16* __restrict__ Ko, u16* __restrict__ Vt,
    float* __restrict__ Co)
{
    __shared__ u16 As[128 * 64];
    __shared__ u16 Bs[128 * 64];

    const int t  = threadIdx.x;
    const int w  = t >> 6, l = t & 63;
    const int wm = w >> 1, wn = w & 1;
    const int lr = l & 15, lh = l >> 4;
    const int n0 = blockIdx.x * 128;
    const int m0 = blockIdx.y * 128;

    f32x4 acc[4][4];
    #pragma unroll
    for (int i = 0; i < 4; ++i)
        #pragma unroll
        for (int j = 0; j < 4; ++j)
            acc[i][j] = (f32x4)0.f;

    const int x  = (w * 4) * 1024 + l * 16;
    for (int k0 = 0; k0 < 2048; k0 += 64) {
        #pragma unroll
        for (int u = 0; u < 4; ++u) {
            int xb = x + u * 1024;
            int r  = xb >> 7;
            int c  = xb & 127;
            int cs = c ^ ((r & 7) << 4);
            gload16(&A[(size_t)(m0 + r) * 2048 + k0 + (cs >> 1)], &As[(w * 4 + u) * 512]);
            gload16(&Bw[(size_t)(n0 + r) * 2048 + k0 + (cs >> 1)], &Bs[(w * 4 + u) * 512]);
        }
        __syncthreads();
        #pragma unroll
        for (int kc = 0; kc < 2; ++kc) {
            bf16x8 af[4], bfr[4];
            #pragma unroll
            for (int i = 0; i < 4; ++i) {
                int row = wm * 64 + i * 16 + lr;
                int byt = row * 128 + ((kc * 64 + lh * 16) ^ ((row & 7) << 4));
                af[i] = *(const bf16x8*)&As[byt >> 1];
                int rob = wn * 64 + i * 16 + lr;
                int byb = rob * 128 + ((kc * 64 + lh * 16) ^ ((rob & 7) << 4));
                bfr[i] = *(const bf16x8*)&Bs[byb >> 1];
            }
            #pragma unroll
            for (int i = 0; i < 4; ++i)
                #pragma unroll
                for (int j = 0; j < 4; ++j)
                    acc[i][j] = __builtin_amdgcn_mfma_f32_16x16x32_bf16(
                        af[i], bfr[j], acc[i][j], 0, 0, 0);
        }
        __syncthreads();
    }

    // epilogue.  C/D layout: row = (l>>4)*4 + reg, col = l&15
    #pragma unroll
    for (int i = 0; i < 4; ++i) {
        #pragma unroll
        for (int j = 0; j < 4; ++j) {
            int col = n0 + wn * 64 + j * 16 + lr;
            #pragma unroll
            for (int r = 0; r < 4; ++r) {
                int m = m0 + wm * 64 + i * 16 + lh * 4 + r;
                float v = acc[i][j][r];
                if (MODE == 0) {
                    int bb = m >> 11, s = m & 2047;
                    if (col < 2048) {
                        int hh = col >> 7, d = col & 127;
                        Qo[((size_t)(bb * H_ + hh) * S_ + s) * HD_ + d] = f2bf(v);
                    } else if (col < 2560) {
                        int c2 = col - 2048; int hh = c2 >> 7, d = c2 & 127;
                        Ko[((size_t)(bb * KVH_ + hh) * S_ + s) * HD_ + d] = f2bf(v);
                    } else {
                        int c2 = col - 2560; int hh = c2 >> 7, d = c2 & 127;
                        Vt[((size_t)(bb * KVH_ + hh) * HD_ + d) * S_ + s] = f2bf(v);
                    }
                } else {
                    Co[(size_t)m * 2048 + col] = v;
                }
            }
        }
    }
}

// ---------------------------------------------------------------------------
// RMSNorm + RoPE in place (bf16).  One wave per 128-elem row.
// Q gets SCALE*LOG2E folded (attention uses exp2 directly).
// ---------------------------------------------------------------------------
__global__ __launch_bounds__(256) void norm_rope(
    u16* __restrict__ Qb, u16* __restrict__ Kb,
    const float* __restrict__ cosb, const float* __restrict__ sinb,
    const float* __restrict__ qnw, const float* __restrict__ knw)
{
    const int rid = blockIdx.x * 4 + (threadIdx.x >> 6);
    const int l   = threadIdx.x & 63;
    u16* row; const float* wn; int s; float sc;
    if (rid < B_ * H_ * S_) {
        row = Qb + (size_t)rid * HD_; wn = qnw; s = rid & (S_ - 1); sc = SCALE * LOG2E;
    } else {
        int r2 = rid - B_ * H_ * S_;
        row = Kb + (size_t)r2 * HD_; wn = knw; s = r2 & (S_ - 1); sc = 1.f;
    }
    unsigned int u = *(const unsigned int*)&row[2 * l];
    float x0 = bf2f((u16)(u & 0xffff)), x1 = bf2f((u16)(u >> 16));
    float ss = x0 * x0 + x1 * x1;
    #pragma unroll
    for (int off = 1; off < 64; off <<= 1) ss += __shfl_xor(ss, off);
    float rr = rsqrtf(ss * (1.f / 128.f) + 1e-6f);
    float n0 = x0 * rr * wn[2 * l];
    float n1 = x1 * rr * wn[2 * l + 1];
    float p0 = __shfl_xor(n0, 32);
    float p1 = __shfl_xor(n1, 32);
    float sg = (l < 32) ? -1.f : 1.f;
    const float* cp = cosb + s * HD_;
    const float* sp = sinb + s * HD_;
    float o0 = (n0 * cp[2 * l]     + sg * p0 * sp[2 * l])     * sc;
    float o1 = (n1 * cp[2 * l + 1] + sg * p1 * sp[2 * l + 1]) * sc;
    unsigned int o = (unsigned int)f2bf(o0) | ((unsigned int)f2bf(o1) << 16);
    *(unsigned int*)&row[2 * l] = o;
}

// ---------------------------------------------------------------------------
// Flash attention, m214 structure: 4 warps x 32 q-rows, KVBLK=64, swapped
// QK^T (mfma(K,Q) -> lane owns one q-row's P), in-register softmax with
// defer-max, cvt_pk+shfl P repack feeding PV's A-operand, double-buffered
// swizzled KV staging with one barrier per tile, XCD-chunked grid.
// ---------------------------------------------------------------------------
__global__ __launch_bounds__(256, 2) void attn_mfma(
    const u16* __restrict__ Q,    // [B*H][S][128], SCALE*LOG2E pre-folded
    const u16* __restrict__ K,    // [B*KVH][S][128]
    const u16* __restrict__ Vt,   // [B*KVH][128][S]
    u16* __restrict__ AO)         // [B][S][2048]
{
    __shared__ u16 Ks[2][64 * 128];     // rows 256B, XOR-swizzled
    __shared__ u16 Vs[2][128 * 64];     // rows 128B, XOR-swizzled

    const int t  = threadIdx.x, w = t >> 6, l = t & 63;
    const int lq = l & 31, hi = l >> 5;
    // XCD-chunked swizzle: 512 blocks, 64/XCD = one (b,kvh) per XCD
    const int id = (blockIdx.x & 7) * 64 + (blockIdx.x >> 3);
    const int qx = id & 15, bh = id >> 4;
    const int bb = bh >> 4, h = bh & 15;
    const int kv = bb * KVH_ + (h >> 2);
    const int q0 = qx * 128 + w * 32;

    const u16* Qp = Q + ((size_t)bh * S_ + q0) * HD_;
    const u16* Kp = K + (size_t)kv * S_ * HD_;
    const u16* Vp = Vt + (size_t)kv * HD_ * S_;

    // Q as B-operand fragments: col=q=lane&31, k-elem j -> d = ks*16 + hi*8 + j
    bf16x8 aq[8];
    #pragma unroll
    for (int ks = 0; ks < 8; ++ks)
        aq[ks] = *(const bf16x8*)&Qp[(size_t)lq * 128 + ks * 16 + hi * 8];

    f32x16 oacc[4];
    #pragma unroll
    for (int dt = 0; dt < 4; ++dt) oacc[dt] = (f32x16)0.f;
    float mrun = -1e30f, lrun = 0.f;

    auto stage = [&](int k0, int buf) {
        #pragma unroll
        for (int u = 0; u < 4; ++u) {
            int xb = (w * 4 + u) * 1024 + l * 16;
            int rk = xb >> 8, ck = xb & 255;
            gload16(&Kp[(size_t)(k0 + rk) * 128 + ((ck ^ ((rk & 7) << 4)) >> 1)],
                    &Ks[buf][(w * 4 + u) * 512]);
            int rv = xb >> 7, cv = xb & 127;
            gload16(&Vp[(size_t)rv * S_ + k0 + ((cv ^ ((rv & 7) << 4)) >> 1)],
                    &Vs[buf][(w * 4 + u) * 512]);
        }
    };

    stage(0, 0);
    __syncthreads();

    const int NT = S_ / 64;
    for (int kt = 0; kt < NT; ++kt) {
        const int cur = kt & 1;
        if (kt + 1 < NT) stage((kt + 1) * 64, cur ^ 1);

        // --- swapped QK^T: S^T[k][q], A=K, B=Q ---
        f32x16 sacc[2];
        sacc[0] = (f32x16)0.f; sacc[1] = (f32x16)0.f;
        #pragma unroll
        for (int kb = 0; kb < 2; ++kb) {
            #pragma unroll
            for (int ks = 0; ks < 8; ++ks) {
                int row = kb * 32 + lq;
                int byt = row * 256 + ((ks * 32 + hi * 16) ^ ((row & 7) << 4));
                bf16x8 kf = *(const bf16x8*)&Ks[cur][byt >> 1];
                sacc[kb] = __builtin_amdgcn_mfma_f32_32x32x16_bf16(
                    kf, aq[ks], sacc[kb], 0, 0, 0);
            }
        }

        // --- in-register online softmax (lane owns q-row lq; halves split k) ---
        float mx = -1e30f;
        #pragma unroll
        for (int kb = 0; kb < 2; ++kb)
            #pragma unroll
            for (int r = 0; r < 16; ++r)
                mx = fmaxf(mx, sacc[kb][r]);
        mx = fmaxf(mx, __shfl_xor(mx, 32));
        if (__any(mx > mrun + 8.f)) {           // defer-max (T13)
            float mn = fmaxf(mrun, mx);
            float al = __builtin_exp2f(mrun - mn);
            mrun = mn;
            lrun *= al;
            #pragma unroll
            for (int r = 0; r < 16; ++r) {
                int src = (r & 3) + 8 * (r >> 2) + 4 * hi;   // output-row owner
                float alr = __shfl(al, src);
                #pragma unroll
                for (int dt = 0; dt < 4; ++dt) oacc[dt][r] *= alr;
            }
        }
        float ps = 0.f;
        #pragma unroll
        for (int kb = 0; kb < 2; ++kb)
            #pragma unroll
            for (int r = 0; r < 16; ++r) {
                float p = __builtin_exp2f(sacc[kb][r] - mrun);
                sacc[kb][r] = p;
                ps += p;
            }
        ps += __shfl_xor(ps, 32);
        lrun += ps;

        // --- P repack (cvt_pk + cross-half exchange) and PV ---
        #pragma unroll
        for (int kb = 0; kb < 2; ++kb) {
            u32 wv[8], sv[8];
            #pragma unroll
            for (int i = 0; i < 8; ++i)
                wv[i] = cvtpk(sacc[kb][2 * i], sacc[kb][2 * i + 1]);
            #pragma unroll
            for (int i = 0; i < 8; ++i)
                sv[i] = __shfl_xor(wv[i], 32);
            #pragma unroll
            for (int k2 = 0; k2 < 2; ++k2) {
                union { u32 u[4]; bf16x8 v; } pa;
                pa.u[0] = hi ? sv[4 * k2 + 2] : wv[4 * k2 + 0];
                pa.u[1] = hi ? sv[4 * k2 + 3] : wv[4 * k2 + 1];
                pa.u[2] = hi ? wv[4 * k2 + 2] : sv[4 * k2 + 0];
                pa.u[3] = hi ? wv[4 * k2 + 3] : sv[4 * k2 + 1];
                int kloc = (kb * 2 + k2) * 16 + hi * 8;      // V k-slice base
                #pragma unroll
                for (int dt = 0; dt < 4; ++dt) {
                    int rowv = dt * 32 + lq;
                    int byv  = rowv * 128 + ((kloc * 2) ^ ((rowv & 7) << 4));
                    bf16x8 vf = *(const bf16x8*)&Vs[cur][byv >> 1];
                    oacc[dt] = __builtin_amdgcn_mfma_f32_32x32x16_bf16(
                        pa.v, vf, oacc[dt], 0, 0, 0);
                }
            }
        }
        __syncthreads();
    }

    // epilogue: O[q'][d], q' = (r&3)+8*(r>>2)+4*hi, d = dt*32+lq
    #pragma unroll
    for (int r = 0; r < 16; ++r) {
        int src = (r & 3) + 8 * (r >> 2) + 4 * hi;
        float linv = 1.f / __shfl(lrun, src);
        int s = q0 + src;
        size_t base = ((size_t)bb * S_ + s) * 2048 + h * 128 + lq;
        #pragma unroll
        for (int dt = 0; dt < 4; ++dt)
            AO[base + dt * 32] = f2bf(oacc[dt][r] * linv);
    }
}

// ---------------------------------------------------------------------------
extern "C" void kernel_launch(void* const* d_in, const int* in_sizes, int n_in,
                              void* d_out, int out_size, void* d_ws, size_t ws_size,
                              hipStream_t stream) {
    (void)in_sizes; (void)n_in; (void)out_size; (void)ws_size;
    const float* hid  = (const float*)d_in[0];
    const float* cosb = (const float*)d_in[1];
    const float* sinb = (const float*)d_in[2];
    const float* qw   = (const float*)d_in[3];
    const float* kw   = (const float*)d_in[4];
    const float* vw   = (const float*)d_in[5];
    const float* ow   = (const float*)d_in[6];
    const float* qnw  = (const float*)d_in[7];
    const float* knw  = (const float*)d_in[8];

    u16* ws   = (u16*)d_ws;
    u16* hidB = ws;                         // 8,388,608
    u16* Wc   = ws + 8388608;               // 6,291,456  (qw|kw|vw rows)
    u16* owB  = ws + 14680064;              // 4,194,304
    u16* Qb   = ws + 18874368;              // 8,388,608  [B*H][S][128]
    u16* Kb   = ws + 27262976;              // 2,097,152  [B*KVH][S][128]
    u16* VtB  = ws + 29360128;              // 2,097,152  [B*KVH][128][S]
    u16* AO   = ws + 31457280;              // 8,388,608  [B][S][2048]

    f2b_kernel<<<8192, 256, 0, stream>>>(hid, hidB, 2097152);
    f2b_kernel<<<4096, 256, 0, stream>>>(qw, Wc, 1048576);
    f2b_kernel<<<1024, 256, 0, stream>>>(kw, Wc + 4194304, 262144);
    f2b_kernel<<<1024, 256, 0, stream>>>(vw, Wc + 5242880, 262144);
    f2b_kernel<<<4096, 256, 0, stream>>>(ow, owB, 1048576);

    gemm_bf16<0><<<dim3(24, 32), 256, 0, stream>>>(hidB, Wc, Qb, Kb, VtB, nullptr);
    norm_rope<<<20480, 256, 0, stream>>>(Qb, Kb, cosb, sinb, qnw, knw);
    attn_mfma<<<512, 256, 0, stream>>>(Qb, Kb, VtB, AO);
    gemm_bf16<1><<<dim3(16, 32), 256, 0, stream>>>(AO, owB, nullptr, nullptr, nullptr,
                                                   (float*)d_out);
}